// Round 8
// baseline (2153.174 us; speedup 1.0000x reference)
//
#include <hip/hip_runtime.h>

typedef float f32x2 __attribute__((ext_vector_type(2)));
typedef float f32x4 __attribute__((ext_vector_type(4)));

#define BB 256
#define TT 1024
#define HH 128
#define CC 2

// tanh(u) = 1 - 2/(exp(2u)+1); branchless. Validated R3-R6: absmax 9.77e-4.
__device__ __forceinline__ float ftanh(float u) {
    float e = __expf(2.0f * u);
    float r = __builtin_amdgcn_rcpf(e + 1.0f);
    return fmaf(-2.0f, r, 1.0f);
}

// broadcast lane j's value to all lanes via SGPR (VALU pipe, no LDS)
__device__ __forceinline__ float bcast(float v, int j) {
    return __int_as_float(__builtin_amdgcn_readlane(__float_as_int(v), j));
}

__global__ __launch_bounds__(64, 1) void rnn_kernel(
    const float* __restrict__ x, const float* __restrict__ W_ih,
    const float* __restrict__ W_hh, const float* __restrict__ b_ih,
    const float* __restrict__ b_hh, const float* __restrict__ W_fc,
    const float* __restrict__ b_fc, float* __restrict__ out)
{
    const int b = blockIdx.x;
    const int l = threadIdx.x;          // 0..63, single wave: no barriers ever
    const int rA = l, rB = l + 64;      // the two rows this lane owns fully

    __shared__ float xs[TT];            // input sequence (4 KB)
    __shared__ f32x4 wlds[32][64];      // streamed weight half, k in [64,128) (32 KB)
                                        // chunk g lane l = {wA_k0,wB_k0,wA_k1,wB_k1}, k0=64+2g

    // preload x row (coalesced f32x4; single wave -> in-order LDS, no barrier)
    {
        const f32x4* xr = (const f32x4*)(x + (size_t)b * TT);
        f32x4* xd = (f32x4*)xs;
        #pragma unroll
        for (int i = 0; i < 4; ++i) xd[l + 64 * i] = xr[l + 64 * i];
    }

    // per-lane constants
    const float wihA  = W_ih[rA],  wihB  = W_ih[rB];
    const float biasA = b_ih[rA] + b_hh[rA];
    const float biasB = b_ih[rB] + b_hh[rB];
    const float wf0A = W_fc[rA],      wf0B = W_fc[rB];        // class 0
    const float wf1A = W_fc[HH + rA], wf1B = W_fc[HH + rB];   // class 1
    const float bf0 = b_fc[0], bf1 = b_fc[1];

    const f32x4* a4 = (const f32x4*)(W_hh + (size_t)rA * HH);
    const f32x4* b4 = (const f32x4*)(W_hh + (size_t)rB * HH);

    // VGPR-resident half: wp[k] = {W[rA][k], W[rB][k]}, k in [0,64) -> 128 VGPRs
    f32x2 wp[64];
    #pragma unroll
    for (int j = 0; j < 16; ++j) {
        f32x4 va = a4[j], vb = b4[j];
        wp[4*j+0] = f32x2{va.x, vb.x};
        wp[4*j+1] = f32x2{va.y, vb.y};
        wp[4*j+2] = f32x2{va.z, vb.z};
        wp[4*j+3] = f32x2{va.w, vb.w};
    }
    // LDS-streamed half: k in [64,128). [g][lane] layout: lanes 16B apart ->
    // conflict-free ds_read_b128 / ds_write_b128.
    #pragma unroll
    for (int j = 0; j < 16; ++j) {
        f32x4 va = a4[16 + j], vb = b4[16 + j];
        wlds[2*j    ][l] = f32x4{va.x, vb.x, va.y, vb.y};
        wlds[2*j + 1][l] = f32x4{va.z, vb.z, va.w, vb.w};
    }

    float hn0 = 0.f, hn1 = 0.f;         // h[rA], h[rB]; h never touches LDS
    float* o = out + (size_t)b * TT * CC;

    #pragma unroll 2
    for (int t = 0; t < TT; ++t) {
        // logit partials of h_t (entry hn) -> out[t-1]
        float q0 = fmaf(wf0A, hn0, wf0B * hn1);
        float q1 = fmaf(wf1A, hn0, wf1B * hn1);

        f32x2 a0 = {0.f,0.f}, a1 = {0.f,0.f}, a2 = {0.f,0.f}, a3 = {0.f,0.f};

        // k in [0,64): VGPR weights, h via readlane of hn0
        #pragma unroll
        for (int k = 0; k < 64; k += 4) {
            float s0 = bcast(hn0, k+0);
            float s1 = bcast(hn0, k+1);
            float s2 = bcast(hn0, k+2);
            float s3 = bcast(hn0, k+3);
            a0 = __builtin_elementwise_fma(wp[k+0], f32x2{s0,s0}, a0);
            a1 = __builtin_elementwise_fma(wp[k+1], f32x2{s1,s1}, a1);
            a2 = __builtin_elementwise_fma(wp[k+2], f32x2{s2,s2}, a2);
            a3 = __builtin_elementwise_fma(wp[k+3], f32x2{s3,s3}, a3);
        }

        // logit xor-tree here: issues between the two fma stages, latency
        // hides under fma issue (not on the recurrence dependency chain)
        q0 += __shfl_xor(q0, 1);  q1 += __shfl_xor(q1, 1);
        q0 += __shfl_xor(q0, 2);  q1 += __shfl_xor(q1, 2);
        q0 += __shfl_xor(q0, 4);  q1 += __shfl_xor(q1, 4);
        q0 += __shfl_xor(q0, 8);  q1 += __shfl_xor(q1, 8);
        q0 += __shfl_xor(q0, 16); q1 += __shfl_xor(q1, 16);
        q0 += __shfl_xor(q0, 32); q1 += __shfl_xor(q1, 32);

        // k in [64,128): streamed LDS weights (h-independent loads -> latency
        // hidden), h via readlane of hn1
        #pragma unroll
        for (int g = 0; g < 32; g += 2) {
            f32x4 w4 = wlds[g][l];
            f32x4 w5 = wlds[g + 1][l];
            float s0 = bcast(hn1, 2*g + 0);
            float s1 = bcast(hn1, 2*g + 1);
            float s2 = bcast(hn1, 2*g + 2);
            float s3 = bcast(hn1, 2*g + 3);
            a0 = __builtin_elementwise_fma(f32x2{w4.x, w4.y}, f32x2{s0,s0}, a0);
            a1 = __builtin_elementwise_fma(f32x2{w4.z, w4.w}, f32x2{s1,s1}, a1);
            a2 = __builtin_elementwise_fma(f32x2{w5.x, w5.y}, f32x2{s2,s2}, a2);
            a3 = __builtin_elementwise_fma(f32x2{w5.z, w5.w}, f32x2{s3,s3}, a3);
        }

        if (t > 0 && l == 0) {
            f32x2 s = {q0 + bf0, q1 + bf1};
            *(f32x2*)(o + (t - 1) * CC) = s;
        }

        f32x2 aa = (a0 + a1) + (a2 + a3);
        const float xt = xs[t];
        hn0 = ftanh(fmaf(xt, wihA, biasA) + aa.x);
        hn1 = ftanh(fmaf(xt, wihB, biasB) + aa.y);
    }

    // epilogue: out[TT-1] = logits(h_TT)
    {
        float q0 = fmaf(wf0A, hn0, wf0B * hn1);
        float q1 = fmaf(wf1A, hn0, wf1B * hn1);
        q0 += __shfl_xor(q0, 1);  q1 += __shfl_xor(q1, 1);
        q0 += __shfl_xor(q0, 2);  q1 += __shfl_xor(q1, 2);
        q0 += __shfl_xor(q0, 4);  q1 += __shfl_xor(q1, 4);
        q0 += __shfl_xor(q0, 8);  q1 += __shfl_xor(q1, 8);
        q0 += __shfl_xor(q0, 16); q1 += __shfl_xor(q1, 16);
        q0 += __shfl_xor(q0, 32); q1 += __shfl_xor(q1, 32);
        if (l == 0) {
            f32x2 s = {q0 + bf0, q1 + bf1};
            *(f32x2*)(o + (TT - 1) * CC) = s;
        }
    }
}

extern "C" void kernel_launch(void* const* d_in, const int* in_sizes, int n_in,
                              void* d_out, int out_size, void* d_ws, size_t ws_size,
                              hipStream_t stream) {
    const float* x    = (const float*)d_in[0];
    const float* W_ih = (const float*)d_in[1];
    const float* W_hh = (const float*)d_in[2];
    const float* b_ih = (const float*)d_in[3];
    const float* b_hh = (const float*)d_in[4];
    const float* W_fc = (const float*)d_in[5];
    const float* b_fc = (const float*)d_in[6];
    float* out = (float*)d_out;

    rnn_kernel<<<BB, 64, 0, stream>>>(x, W_ih, W_hh, b_ih, b_hh, W_fc, b_fc, out);
}

// Round 10
// 511.448 us; speedup vs baseline: 4.2100x; 4.2100x over previous
//
#include <hip/hip_runtime.h>

typedef float f32x2 __attribute__((ext_vector_type(2)));
typedef float f32x4 __attribute__((ext_vector_type(4)));

#define BB 256
#define TT 1024
#define HH 128
#define CC 2

// tanh(u) = 1 - 2/(exp(2u)+1); branchless. Validated R3-R7: absmax 9.77e-4.
__device__ __forceinline__ float ftanh(float u) {
    float e = __expf(2.0f * u);
    float r = __builtin_amdgcn_rcpf(e + 1.0f);
    return fmaf(-2.0f, r, 1.0f);
}

// broadcast lane j's value to all lanes via SGPR (VALU pipe, no LDS)
__device__ __forceinline__ float bcast(float v, int j) {
    return __int_as_float(__builtin_amdgcn_readlane(__float_as_int(v), j));
}

__global__ __launch_bounds__(256, 1) void rnn_kernel(
    const float* __restrict__ x, const float* __restrict__ W_ih,
    const float* __restrict__ W_hh, const float* __restrict__ b_ih,
    const float* __restrict__ b_hh, const float* __restrict__ W_fc,
    const float* __restrict__ b_fc, float* __restrict__ out)
{
    const int b   = blockIdx.x;
    const int tid = threadIdx.x;        // 0..255
    const int l   = tid & 63;
    const int wv  = tid >> 6;           // 0..3
    const int lq  = l & 31;
    const int kb  = wv << 5;            // this wave's k-quarter base
    const int rA  = l, rB = l + 64;     // partial rows this lane computes
    const int rF  = kb + lq;            // row this wave finalizes (dup in lanes 32..63)

    __shared__ float xs[TT + 8];        // input sequence (+pad for prefetch)
    __shared__ f32x2 p2[2][4][64];      // [buf][src wave][lane] = {pA, pB}
    __shared__ f32x2 qp[4][4];          // [t&3][wave] logit partials

    // preload x row (256 lanes x f32x4, coalesced)
    {
        const f32x4* xr = (const f32x4*)(x + (size_t)b * TT);
        ((f32x4*)xs)[tid] = xr[tid];
    }
    if (tid < 8) xs[TT + tid] = 0.f;    // prefetch pad

    const float wih  = W_ih[rF];
    const float bias = b_ih[rF] + b_hh[rF];
    const float wf0  = W_fc[rF];
    const float wf1  = W_fc[HH + rF];
    const float bf0  = b_fc[0], bf1 = b_fc[1];

    // per-lane weights: rows rA,rB over k in [kb, kb+32) -> 64 floats.
    // asm-pinned so the allocator CANNOT rematerialize the loads inside the
    // K-loop (R6's failure: VGPR=48 => per-step global reloads on the chain).
    float wa[32], wb[32];
    {
        const f32x4* a4 = (const f32x4*)(W_hh + (size_t)rA * HH + kb);
        const f32x4* b4 = (const f32x4*)(W_hh + (size_t)rB * HH + kb);
        #pragma unroll
        for (int j = 0; j < 8; ++j) {
            f32x4 va = a4[j], vb = b4[j];
            wa[4*j+0] = va.x; wa[4*j+1] = va.y; wa[4*j+2] = va.z; wa[4*j+3] = va.w;
            wb[4*j+0] = vb.x; wb[4*j+1] = vb.y; wb[4*j+2] = vb.z; wb[4*j+3] = vb.w;
        }
        #pragma unroll
        for (int k = 0; k < 32; ++k)
            asm volatile("" : "+v"(wa[k]), "+v"(wb[k]));
    }

    float hn = 0.f;                     // h_t[rF] (lanes 32..63 duplicate 0..31)
    float* o = out + (size_t)b * TT * CC;

    __syncthreads();                    // xs visible
    float xcur = xs[0];

    #pragma unroll 4
    for (int t = 0; t < TT; ++t) {
        const int buf = t & 1, qb = t & 3;

        // ---- partial matvec over this wave's k-quarter; h via readlane.
        // lane k (k<32) holds h[kb+k] in hn -> bcast(hn,k) = h[kb+k].
        float aA0 = 0.f, aA1 = 0.f, aB0 = 0.f, aB1 = 0.f;
        #pragma unroll
        for (int k = 0; k < 32; k += 2) {
            float s0 = bcast(hn, k);
            float s1 = bcast(hn, k + 1);
            aA0 = fmaf(wa[k],     s0, aA0);
            aB0 = fmaf(wb[k],     s0, aB0);
            aA1 = fmaf(wa[k + 1], s1, aA1);
            aB1 = fmaf(wb[k + 1], s1, aB1);
        }
        f32x2 pr = { aA0 + aA1, aB0 + aB1 };
        p2[buf][wv][l] = pr;            // b64 ship, 2-way alias = free

        // ---- logit partials of h_t over this wave's 32 rows (lanes 0..31)
        float q0 = wf0 * hn, q1 = wf1 * hn;
        if (l >= 32) { q0 = 0.f; q1 = 0.f; }
        q0 += __shfl_xor(q0, 1);  q1 += __shfl_xor(q1, 1);
        q0 += __shfl_xor(q0, 2);  q1 += __shfl_xor(q1, 2);
        q0 += __shfl_xor(q0, 4);  q1 += __shfl_xor(q1, 4);
        q0 += __shfl_xor(q0, 8);  q1 += __shfl_xor(q1, 8);
        q0 += __shfl_xor(q0, 16); q1 += __shfl_xor(q1, 16);
        if (l == 0) qp[qb][wv] = f32x2{q0, q1};

        // pre-barrier: u-base and x prefetch (keeps them off post-barrier chain)
        const float base  = fmaf(xcur, wih, bias);
        const float xnext = xs[t + 1];

        __syncthreads();                // the single per-step barrier

        // ---- out[t-1] = logits(h_t): qp[t&3] was written THIS iteration
        // pre-barrier (R8 bug: used qp[(t-1)&3] -> one step stale).
        if (t > 0 && tid == 0) {
            f32x2 s = (qp[qb][0] + qp[qb][1]) + (qp[qb][2] + qp[qb][3]);
            s.x += bf0; s.y += bf1;
            *(f32x2*)(o + (t - 1) * CC) = s;
        }

        // ---- combine the 4 k-quarter partials of row rF (conflict-free b32)
        const float* pf = (const float*)&p2[buf][0][0]
                        + ((((wv & 1) << 5) + lq) << 1) + (wv >> 1);
        float p0 = pf[0], p1 = pf[128], pv2 = pf[256], pv3 = pf[384];
        hn = ftanh(base + ((p0 + p1) + (pv2 + pv3)));
        xcur = xnext;
    }

    // epilogue: out[TT-1] = logits(h_TT)
    {
        float q0 = wf0 * hn, q1 = wf1 * hn;
        if (l >= 32) { q0 = 0.f; q1 = 0.f; }
        q0 += __shfl_xor(q0, 1);  q1 += __shfl_xor(q1, 1);
        q0 += __shfl_xor(q0, 2);  q1 += __shfl_xor(q1, 2);
        q0 += __shfl_xor(q0, 4);  q1 += __shfl_xor(q1, 4);
        q0 += __shfl_xor(q0, 8);  q1 += __shfl_xor(q1, 8);
        q0 += __shfl_xor(q0, 16); q1 += __shfl_xor(q1, 16);
        if (l == 0) qp[0][wv] = f32x2{q0, q1};
    }
    __syncthreads();
    if (tid == 0) {
        f32x2 s = (qp[0][0] + qp[0][1]) + (qp[0][2] + qp[0][3]);
        s.x += bf0; s.y += bf1;
        *(f32x2*)(o + (TT - 1) * CC) = s;
    }
}

extern "C" void kernel_launch(void* const* d_in, const int* in_sizes, int n_in,
                              void* d_out, int out_size, void* d_ws, size_t ws_size,
                              hipStream_t stream) {
    const float* x    = (const float*)d_in[0];
    const float* W_ih = (const float*)d_in[1];
    const float* W_hh = (const float*)d_in[2];
    const float* b_ih = (const float*)d_in[3];
    const float* b_hh = (const float*)d_in[4];
    const float* W_fc = (const float*)d_in[5];
    const float* b_fc = (const float*)d_in[6];
    float* out = (float*)d_out;

    rnn_kernel<<<BB, 256, 0, stream>>>(x, W_ih, W_hh, b_ih, b_hh, W_fc, b_fc, out);
}

// Round 11
// 464.203 us; speedup vs baseline: 4.6384x; 1.1018x over previous
//
#include <hip/hip_runtime.h>

typedef float f32x2 __attribute__((ext_vector_type(2)));
typedef float f32x4 __attribute__((ext_vector_type(4)));

#define BB 256
#define TT 1024
#define HH 128
#define CC 2

// tanh(u) = 1 - 2/(exp(2u)+1); branchless. Validated R3-R9: absmax 9.77e-4.
__device__ __forceinline__ float ftanh(float u) {
    float e = __expf(2.0f * u);
    float r = __builtin_amdgcn_rcpf(e + 1.0f);
    return fmaf(-2.0f, r, 1.0f);
}

// broadcast lane j's value to all lanes via SGPR (VALU pipe, no LDS)
__device__ __forceinline__ float bcast(float v, int j) {
    return __int_as_float(__builtin_amdgcn_readlane(__float_as_int(v), j));
}

// v + (v cross-lane via DPP): VALU pipe, no LDS. ctrl: 0xB1=quad xor1,
// 0x4E=quad xor2, 0x124=row_ror:4, 0x128=row_ror:8.
#define DPP_ADD(v, ctrl)                                                     \
    ((v) + __int_as_float(__builtin_amdgcn_mov_dpp(                          \
         __float_as_int(v), (ctrl), 0xF, 0xF, true)))

// sum within each row-of-16, then across the 4 rows via readlane. All VALU.
__device__ __forceinline__ float wave_sum(float q) {
    q = DPP_ADD(q, 0xB1);    // + xor1  (quad)
    q = DPP_ADD(q, 0x4E);    // + xor2  (quad)
    q = DPP_ADD(q, 0x124);   // + ror4  (row16)
    q = DPP_ADD(q, 0x128);   // + ror8  (row16) -> each lane = its row16 sum
    return bcast(q, 0) + bcast(q, 16) + bcast(q, 32) + bcast(q, 48);
}

__global__ __launch_bounds__(256, 1) void rnn_kernel(
    const float* __restrict__ x, const float* __restrict__ W_ih,
    const float* __restrict__ W_hh, const float* __restrict__ b_ih,
    const float* __restrict__ b_hh, const float* __restrict__ W_fc,
    const float* __restrict__ b_fc, float* __restrict__ out)
{
    const int b   = blockIdx.x;
    const int tid = threadIdx.x;        // 0..255
    const int l   = tid & 63;
    const int wv  = tid >> 6;           // 0..3
    const int lq  = l & 31;
    const int kb  = wv << 5;            // this wave's k-quarter base
    const int rA  = l, rB = l + 64;     // partial rows this lane computes
    const int rF  = kb + lq;            // row this wave finalizes (dup in lanes 32..63)

    __shared__ float xs[TT + 8];        // input sequence (+pad for prefetch)
    __shared__ f32x2 p2[2][4][64];      // [buf][src wave][lane] = {pA, pB}
    __shared__ f32x2 qp[4][4];          // [t&3][wave] logit partials

    // preload x row (256 lanes x f32x4, coalesced)
    {
        const f32x4* xr = (const f32x4*)(x + (size_t)b * TT);
        ((f32x4*)xs)[tid] = xr[tid];
    }
    if (tid < 8) xs[TT + tid] = 0.f;    // prefetch pad

    const float wih  = W_ih[rF];
    const float bias = b_ih[rF] + b_hh[rF];
    // halved: all 64 lanes contribute, lanes 32..63 duplicate rows -> x2
    const float wf0  = 0.5f * W_fc[rF];
    const float wf1  = 0.5f * W_fc[HH + rF];
    const float bf0  = b_fc[0], bf1 = b_fc[1];

    // per-lane weights: rows rA,rB over k in [kb, kb+32) -> 64 floats.
    float wa[32], wb[32];
    {
        const f32x4* a4 = (const f32x4*)(W_hh + (size_t)rA * HH + kb);
        const f32x4* b4 = (const f32x4*)(W_hh + (size_t)rB * HH + kb);
        #pragma unroll
        for (int j = 0; j < 8; ++j) {
            f32x4 va = a4[j], vb = b4[j];
            wa[4*j+0] = va.x; wa[4*j+1] = va.y; wa[4*j+2] = va.z; wa[4*j+3] = va.w;
            wb[4*j+0] = vb.x; wb[4*j+1] = vb.y; wb[4*j+2] = vb.z; wb[4*j+3] = vb.w;
        }
        #pragma unroll
        for (int k = 0; k < 32; ++k)
            asm volatile("" : "+v"(wa[k]), "+v"(wb[k]));
    }

    float hn = 0.f;                     // h_t[rF] (lanes 32..63 duplicate 0..31)
    float* o = out + (size_t)b * TT * CC;

    __syncthreads();                    // xs visible
    float xcur = xs[0];

    #pragma unroll 4
    for (int t = 0; t < TT; ++t) {
        const int buf = t & 1, qb = t & 3;

        // ---- partial matvec over this wave's k-quarter; h via readlane.
        float aA0 = 0.f, aA1 = 0.f, aB0 = 0.f, aB1 = 0.f;
        #pragma unroll
        for (int k = 0; k < 32; k += 2) {
            float s0 = bcast(hn, k);
            float s1 = bcast(hn, k + 1);
            aA0 = fmaf(wa[k],     s0, aA0);
            aB0 = fmaf(wb[k],     s0, aB0);
            aA1 = fmaf(wa[k + 1], s1, aA1);
            aB1 = fmaf(wb[k + 1], s1, aB1);
        }
        f32x2 pr = { aA0 + aA1, aB0 + aB1 };
        p2[buf][wv][l] = pr;            // b64 ship, 2-way alias = free

        // ---- logit partials of h_t: VALU-only DPP reduction (no LDS chain)
        float q0 = wave_sum(wf0 * hn);
        float q1 = wave_sum(wf1 * hn);
        if (l == 0) qp[qb][wv] = f32x2{q0, q1};

        // pre-barrier: u-base and x prefetch (keeps them off post-barrier chain)
        const float base  = fmaf(xcur, wih, bias);
        const float xnext = xs[t + 1];

        __syncthreads();                // the single per-step barrier

        // ---- out[t-1] = logits(h_t): qp[t&3] written THIS iteration pre-barrier
        if (t > 0 && tid == 0) {
            f32x2 s = (qp[qb][0] + qp[qb][1]) + (qp[qb][2] + qp[qb][3]);
            s.x += bf0; s.y += bf1;
            *(f32x2*)(o + (t - 1) * CC) = s;
        }

        // ---- combine the 4 k-quarter partials of row rF (conflict-free b32)
        const float* pf = (const float*)&p2[buf][0][0]
                        + ((((wv & 1) << 5) + lq) << 1) + (wv >> 1);
        float p0 = pf[0], p1 = pf[128], pv2 = pf[256], pv3 = pf[384];
        hn = ftanh(base + ((p0 + p1) + (pv2 + pv3)));
        xcur = xnext;
    }

    // epilogue: out[TT-1] = logits(h_TT)
    {
        float q0 = wave_sum(wf0 * hn);
        float q1 = wave_sum(wf1 * hn);
        if (l == 0) qp[0][wv] = f32x2{q0, q1};
    }
    __syncthreads();
    if (tid == 0) {
        f32x2 s = (qp[0][0] + qp[0][1]) + (qp[0][2] + qp[0][3]);
        s.x += bf0; s.y += bf1;
        *(f32x2*)(o + (TT - 1) * CC) = s;
    }
}

extern "C" void kernel_launch(void* const* d_in, const int* in_sizes, int n_in,
                              void* d_out, int out_size, void* d_ws, size_t ws_size,
                              hipStream_t stream) {
    const float* x    = (const float*)d_in[0];
    const float* W_ih = (const float*)d_in[1];
    const float* W_hh = (const float*)d_in[2];
    const float* b_ih = (const float*)d_in[3];
    const float* b_hh = (const float*)d_in[4];
    const float* W_fc = (const float*)d_in[5];
    const float* b_fc = (const float*)d_in[6];
    float* out = (float*)d_out;

    rnn_kernel<<<BB, 256, 0, stream>>>(x, W_ih, W_hh, b_ih, b_hh, W_fc, b_fc, out);
}